// Round 2
// 643.847 us; speedup vs baseline: 1.0365x; 1.0365x over previous
//
#include <hip/hip_runtime.h>

typedef __bf16 bf16;
typedef __attribute__((ext_vector_type(8))) __bf16 bf16x8;
typedef __attribute__((ext_vector_type(4))) __bf16 bf16x4;
typedef __attribute__((ext_vector_type(4))) float f32x4;

#define B_ 16
#define C_ 768
#define T_ 1024
#define S_ 12
#define NNEG_ 10
#define NCOPY 11
#define NPRED_ROWS 195360            // 16 * sum_{s=0..11}(1023-s)
#define NPRED (NPRED_ROWS * NCOPY)   // 2148960
#define NT_ 12                       // K tiles: 768 / 64

__device__ __forceinline__ void gload16(const void* g, void* l) {
    __builtin_amdgcn_global_load_lds(
        (__attribute__((address_space(1))) void*)g,
        (__attribute__((address_space(3))) void*)l, 16, 0, 0);
}

// ---------- W [C][C][S] fp32 -> WtT [S][D=C][C] bf16 ----------
__global__ void k_wt(const float* __restrict__ W, bf16* __restrict__ WtT) {
    int id = blockIdx.x * blockDim.x + threadIdx.x;   // id = d*768 + c
    if (id >= C_ * C_) return;
    int d = id / C_, c = id % C_;
    const float* src = W + ((size_t)c * C_ + d) * S_;
#pragma unroll
    for (int s = 0; s < S_; ++s)
        WtT[(size_t)s * C_ * C_ + id] = (bf16)src[s];
}

// ---------- x,y [16][C][T] fp32 (batches b0..b0+cb) -> xTc,yTc [cb][T][C] bf16 ----------
__global__ void k_tr2(const float* __restrict__ x, const float* __restrict__ y,
                      bf16* __restrict__ xTc, bf16* __restrict__ yTc, int b0, int cb) {
    __shared__ float tile[32][33];
    int zz = blockIdx.z;
    const float* src = (zz < cb) ? x : y;
    bf16* dst = (zz < cb) ? xTc : yTc;
    int bb = (zz < cb) ? zz : zz - cb;
    int b = b0 + bb;
    int c0 = blockIdx.y * 32, t0 = blockIdx.x * 32;
    int tx = threadIdx.x & 31, ty = threadIdx.x >> 5;  // ty 0..7
#pragma unroll
    for (int i = 0; i < 4; ++i)
        tile[ty + i * 8][tx] = src[((size_t)b * C_ + c0 + ty + i * 8) * T_ + t0 + tx];
    __syncthreads();
#pragma unroll
    for (int i = 0; i < 4; ++i)
        dst[((size_t)bb * T_ + t0 + ty + i * 8) * C_ + c0 + tx] = (bf16)tile[tx][ty + i * 8];
}

// ---------- Phase 1: P[bb][t][n] = sum_c WtT[n][c]*xTc[bb][t][c] + bias[n%768]
// 256x256 tile, BK=64, 8 waves (2M x 4N), per-wave 128x64 output.
// 8-phase schedule (T2 swizzle + T3/T4 counted vmcnt + T5 setprio):
//   per K-tile, 4 phases of 16 MFMA; region-chased staging so vmcnt(6) never drains.
// LDS: 2 buffers x (A 256x64 + B 256x64) bf16 = 128 KiB -> 1 block/CU.
// Swizzle: read colbyte ^= ((row&7)<<4); inverse pre-applied to the global source
// (global_load_lds writes linearly: dest = base + lane*16).
// b01 is RE-READ from LDS in P3 (region R1 of buf cur is untouched within the
// iteration) to keep per-phase live fragments at 48 VGPRs -> no spill risk.
#define SBAR()  __builtin_amdgcn_s_barrier()
#define SCHED() __builtin_amdgcn_sched_barrier(0)
#define LGKM0() asm volatile("s_waitcnt lgkmcnt(0)" ::: "memory")

__global__ __launch_bounds__(512, 2) void k_gemm8(
    const bf16* __restrict__ xTc, const bf16* __restrict__ WtT,
    const float* __restrict__ bias, bf16* __restrict__ P)
{
    // XCD-contiguous block swizzle (gridDim.x = cb*144, always divisible by 8)
    const int q    = gridDim.x >> 3;
    const int orig = blockIdx.x;
    const int id2  = (orig & 7) * q + (orig >> 3);
    const int bb   = id2 / 144;
    const int rem  = id2 % 144;
    const int tblk = rem / 36;     // t0 = tblk*256
    const int nblk = rem % 36;     // n0 = nblk*256

    const int tid  = threadIdx.x;
    const int wv   = tid >> 6, lane = tid & 63;
    const int mwz  = wv >> 2, nwz = wv & 3;       // 2 x 4 wave grid
    const int quad = lane >> 4, l15 = lane & 15;

    __shared__ __align__(16) bf16 sA[2][256][64];
    __shared__ __align__(16) bf16 sB[2][256][64];

    // ---- staging (write) addressing ----
    // one gload16 = 64 lanes x 16B = 8 rows x 128B; lane covers row (lane>>3), slot (lane&7).
    // global source pre-swizzled: content for phys slot p of row r comes from col p^((r&7)<<4).
    const int lrow = lane >> 3;
    const int laneOff = lrow * 1536 + (((lane & 7) * 16) ^ (lrow << 4));
    const char* aG = (const char*)(WtT + (size_t)(nblk * 256) * C_) + laneOff;
    const char* bG = (const char*)(xTc + ((size_t)bb * T_ + tblk * 256) * C_) + laneOff;
    // wave chunk row bases: A regions are 64-row runs (R0: rows 0-63,128-191; R2:+64),
    // B regions are 32-row runs (R1: rows 0-31,64-95,128-159,192-223; R3:+32).
    const int h0 = wv * 16, h1 = wv * 16 + 8;
    const int arw0 = (h0 & 63) + ((h0 >> 6) << 7);
    const int arw1 = (h1 & 63) + ((h1 >> 6) << 7);
    const int brw0 = (h0 & 31) + ((h0 >> 5) << 6);
    const int brw1 = (h1 & 31) + ((h1 >> 5) << 6);

#define STAGE_A(bufn, roff, kt) do { \
    gload16(aG + (size_t)(arw0 + (roff)) * 1536 + (kt) * 128, &sA[bufn][arw0 + (roff)][0]); \
    gload16(aG + (size_t)(arw1 + (roff)) * 1536 + (kt) * 128, &sA[bufn][arw1 + (roff)][0]); \
} while (0)
#define STAGE_B(bufn, roff, kt) do { \
    gload16(bG + (size_t)(brw0 + (roff)) * 1536 + (kt) * 128, &sB[bufn][brw0 + (roff)][0]); \
    gload16(bG + (size_t)(brw1 + (roff)) * 1536 + (kt) * 128, &sB[bufn][brw1 + (roff)][0]); \
} while (0)

    // ---- fragment (read) addressing: row = base + l15, k-slice = kk*32 + quad*8 ----
    const int csw0 = (quad * 16) ^ ((l15 & 7) << 4);
    const int csw1 = (64 + quad * 16) ^ ((l15 & 7) << 4);
    const char* aRd0 = (const char*)&sA[0][mwz * 128 + l15][0] + csw0;
    const char* aRd1 = (const char*)&sA[0][mwz * 128 + l15][0] + csw1;
    const char* bRd0 = (const char*)&sB[0][nwz * 64 + l15][0] + csw0;
    const char* bRd1 = (const char*)&sB[0][nwz * 64 + l15][0] + csw1;

    f32x4 acc[8][4] = {};

    // ---- prologue: stage T0.{R0,R2,R3,R1} then T1.{R0,R3,R2} (7 chunks, 14 loads) ----
    STAGE_A(0, 0, 0);
    STAGE_A(0, 64, 0);
    STAGE_B(0, 32, 0);
    STAGE_B(0, 0, 0);
    STAGE_A(1, 0, 1);
    STAGE_B(1, 32, 1);
    STAGE_A(1, 64, 1);
    asm volatile("s_waitcnt vmcnt(6)" ::: "memory");   // T0 complete, T1 in flight
    SCHED(); SBAR(); SCHED();

#pragma unroll 2
    for (int j = 0; j < NT_; ++j) {
        const int cur = j & 1;
        const int coff = cur << 15;
        const char* aC0 = aRd0 + coff; const char* aC1 = aRd1 + coff;
        const char* bC0 = bRd0 + coff; const char* bC1 = bRd1 + coff;

        bf16x8 a03[4][2], a47[4][2], b01[2][2], b23[2][2], b01p[2][2];

        // ---------------- P0: M0-3 x N0-1 | stage T(j+1).R1 -> buf^1 ----------------
        if (j + 1 < NT_) STAGE_B(cur ^ 1, 0, j + 1);
#pragma unroll
        for (int i = 0; i < 4; ++i) {
            a03[i][0] = *(const bf16x8*)(aC0 + i * 2048);
            a03[i][1] = *(const bf16x8*)(aC1 + i * 2048);
        }
#pragma unroll
        for (int i = 0; i < 2; ++i) {
            b01[i][0] = *(const bf16x8*)(bC0 + i * 2048);
            b01[i][1] = *(const bf16x8*)(bC1 + i * 2048);
        }
        SCHED(); SBAR(); LGKM0(); SCHED();
        __builtin_amdgcn_s_setprio(1);
#pragma unroll
        for (int i = 0; i < 4; ++i)
#pragma unroll
            for (int n = 0; n < 2; ++n)
#pragma unroll
                for (int kk = 0; kk < 2; ++kk)
                    acc[i][n] = __builtin_amdgcn_mfma_f32_16x16x32_bf16(a03[i][kk], b01[n][kk], acc[i][n], 0, 0, 0);
        __builtin_amdgcn_s_setprio(0);
        SCHED(); SBAR(); SCHED();

        // ---------------- P1: M0-3 x N2-3 | stage T(j+2).R0 (R0 died at P0) --------
        if (j + 2 < NT_) STAGE_A(cur, 0, j + 2);
#pragma unroll
        for (int i = 0; i < 2; ++i) {
            b23[i][0] = *(const bf16x8*)(bC0 + 4096 + i * 2048);
            b23[i][1] = *(const bf16x8*)(bC1 + 4096 + i * 2048);
        }
        SCHED(); SBAR(); LGKM0(); SCHED();
        __builtin_amdgcn_s_setprio(1);
#pragma unroll
        for (int i = 0; i < 4; ++i)
#pragma unroll
            for (int n = 0; n < 2; ++n)
#pragma unroll
                for (int kk = 0; kk < 2; ++kk)
                    acc[i][2 + n] = __builtin_amdgcn_mfma_f32_16x16x32_bf16(a03[i][kk], b23[n][kk], acc[i][2 + n], 0, 0, 0);
        __builtin_amdgcn_s_setprio(0);
        SCHED(); SBAR(); SCHED();

        // ---------------- P2: M4-7 x N2-3 | stage T(j+2).R3 (R3 died at P1) --------
        if (j + 2 < NT_) STAGE_B(cur, 32, j + 2);
#pragma unroll
        for (int i = 0; i < 4; ++i) {
            a47[i][0] = *(const bf16x8*)(aC0 + 8192 + i * 2048);
            a47[i][1] = *(const bf16x8*)(aC1 + 8192 + i * 2048);
        }
        SCHED(); SBAR(); LGKM0(); SCHED();
        __builtin_amdgcn_s_setprio(1);
#pragma unroll
        for (int i = 0; i < 4; ++i)
#pragma unroll
            for (int n = 0; n < 2; ++n)
#pragma unroll
                for (int kk = 0; kk < 2; ++kk)
                    acc[4 + i][2 + n] = __builtin_amdgcn_mfma_f32_16x16x32_bf16(a47[i][kk], b23[n][kk], acc[4 + i][2 + n], 0, 0, 0);
        __builtin_amdgcn_s_setprio(0);
        SCHED(); SBAR(); SCHED();

        // ---------------- P3: M4-7 x N0-1 | stage T(j+2).R2 (R2 died at P2) --------
        // b01 re-read from LDS (region R1 of buf cur untouched this iteration).
        // gate: T(j+1) must be complete; 6 newest loads = this tile's P1/P2/P3 stages.
        if (j + 2 < NT_) STAGE_A(cur, 64, j + 2);
#pragma unroll
        for (int i = 0; i < 2; ++i) {
            b01p[i][0] = *(const bf16x8*)(bC0 + i * 2048);
            b01p[i][1] = *(const bf16x8*)(bC1 + i * 2048);
        }
        if (j < NT_ - 2)       { asm volatile("s_waitcnt vmcnt(6)" ::: "memory"); }
        else if (j == NT_ - 2) { asm volatile("s_waitcnt vmcnt(0)" ::: "memory"); }
        SCHED(); SBAR(); LGKM0(); SCHED();
        __builtin_amdgcn_s_setprio(1);
#pragma unroll
        for (int i = 0; i < 4; ++i)
#pragma unroll
            for (int n = 0; n < 2; ++n)
#pragma unroll
                for (int kk = 0; kk < 2; ++kk)
                    acc[4 + i][n] = __builtin_amdgcn_mfma_f32_16x16x32_bf16(a47[i][kk], b01p[n][kk], acc[4 + i][n], 0, 0, 0);
        __builtin_amdgcn_s_setprio(0);
        SCHED(); SBAR(); SCHED();
    }

    // ---- epilogue: D row (M=n) = quad*4+r, col (N=t) = l15 ----
    const size_t SC = (size_t)S_ * C_;
    bf16* Pb = P + ((size_t)bb * T_) * SC;
#pragma unroll
    for (int i = 0; i < 8; ++i) {
        const int nloc = mwz * 128 + i * 16 + quad * 4;
        const f32x4 bv = *(const f32x4*)&bias[(nblk % 3) * 256 + nloc];
#pragma unroll
        for (int n = 0; n < 4; ++n) {
            const int t = tblk * 256 + nwz * 64 + n * 16 + l15;
            bf16x4 v;
#pragma unroll
            for (int r = 0; r < 4; ++r) v[r] = (bf16)(acc[i][n][r] + bv[r]);
            *(bf16x4*)&Pb[(size_t)t * SC + nblk * 256 + nloc] = v;
        }
    }
#undef STAGE_A
#undef STAGE_B
}

// ---------- Phase 2: one wave per (bb, tp). p[s][n] = sum_d proj[t=tp-1-s][s][d]*tar[n][d]
__global__ __launch_bounds__(256) void k_pred(
    const bf16* __restrict__ P, const bf16* __restrict__ yTc,
    const int* __restrict__ neg, float* __restrict__ out, int b0)
{
    const int widx = (blockIdx.x << 2) + (threadIdx.x >> 6);
    const int lane = threadIdx.x & 63;
    const int bb = widx >> 10, tp = widx & 1023;
    const int b = b0 + bb;
    const int quad = lane >> 4, l15 = lane & 15;

    int sA = l15 < S_ ? l15 : S_ - 1;
    int tA = tp - 1 - sA;
    if (tA < 0) tA = 0;
    const bf16* arow = P + ((size_t)bb * T_ + tA) * (S_ * C_) + sA * C_ + quad * 8;

    int ridx;
    if (l15 == 0)            ridx = bb * T_ + tp;
    else if (l15 < NCOPY)    ridx = neg[(size_t)b * (NNEG_ * T_) + (l15 - 1) * T_ + tp] - b0 * T_;
    else                     ridx = bb * T_ + tp;
    const bf16* brow = yTc + (size_t)ridx * C_ + quad * 8;

    f32x4 acc = {};
#pragma unroll 4
    for (int kt = 0; kt < C_ / 32; ++kt) {
        bf16x8 av = *(const bf16x8*)(arow + kt * 32);
        bf16x8 bv = *(const bf16x8*)(brow + kt * 32);
        acc = __builtin_amdgcn_mfma_f32_16x16x32_bf16(av, bv, acc, 0, 0, 0);
    }

#pragma unroll
    for (int r = 0; r < 4; ++r) {
        int s = quad * 4 + r;
        int t = tp - 1 - s;
        if (s < S_ && t >= 0) {
            int rowbase = s * (T_ - 1) - (s * (s - 1)) / 2;
            size_t row = (size_t)(rowbase + t) * B_ + b;
            if (l15 < NCOPY)       out[row * NCOPY + l15] = acc[r];
            else if (l15 == NCOPY) out[NPRED + row] = 0.0f;   // labels
        }
    }
}

extern "C" void kernel_launch(void* const* d_in, const int* in_sizes, int n_in,
                              void* d_out, int out_size, void* d_ws, size_t ws_size,
                              hipStream_t stream) {
    const float* x    = (const float*)d_in[0];
    const float* y    = (const float*)d_in[1];
    const float* W    = (const float*)d_in[2];
    const float* bias = (const float*)d_in[3];
    const int*   neg  = (const int*)d_in[4];
    float* out = (float*)d_out;

    const size_t offW    = (size_t)S_ * C_ * C_ * 2;        // 14,155,776
    const size_t perb_xy = (size_t)T_ * C_ * 2;             // 1,572,864
    const size_t perb_p  = (size_t)T_ * S_ * C_ * 2;        // 18,874,368
    const size_t perb    = 2 * perb_xy + perb_p;

    int bchunk = (int)((ws_size - offW) / perb);
    if (bchunk < 1) bchunk = 1;
    if (bchunk > B_) bchunk = B_;

    char* ws = (char*)d_ws;
    bf16* WtT = (bf16*)ws;
    bf16* xTc = (bf16*)(ws + offW);
    bf16* yTc = (bf16*)(ws + offW + (size_t)bchunk * perb_xy);
    bf16* P   = (bf16*)(ws + offW + (size_t)bchunk * perb_xy * 2);

    k_wt<<<dim3((C_ * C_ + 255) / 256), 256, 0, stream>>>(W, WtT);

    for (int b0 = 0; b0 < B_;) {
        int cb = bchunk < (B_ - b0) ? bchunk : (B_ - b0);
        k_tr2<<<dim3(T_ / 32, C_ / 32, 2 * cb), 256, 0, stream>>>(x, y, xTc, yTc, b0, cb);
        k_gemm8<<<dim3(cb * 144), 512, 0, stream>>>(xTc, WtT, bias, P);
        k_pred<<<dim3(cb * 256), 256, 0, stream>>>(P, yTc, neg, out, b0);
        b0 += cb;
    }
}